// Round 2
// baseline (714.343 us; speedup 1.0000x reference)
//
#include <hip/hip_runtime.h>
#include <math.h>

// FFM forward: out[b] = sigmoid( bias + sum_f Wl[g(b,f)]
//                                + sum_{i<j} dot(W[j, g(b,i)], W[i, g(b,j)]) )
// g(b,f) = x[b,f] + f*V_FIELD.
//
// R4: XCD-local-L2 gather. R3 showed time is invariant to HBM-byte savings
// -> the wall is the L2-miss path (per-XCD miss-queue occupancy x L3 latency,
// ~1.2 TB/s for random 64B lines), not HBM bytes. Fix: give each XCD its own
// pair subset (pair p -> XCD p%8 via the round-robin block->XCD mapping).
// Each XCD's 256 blocks sweep their 23-24 pairs in lockstep; at each pair the
// blocks cooperatively STREAM the pair's 2.56 MB slice (fits the 4 MB XCD L2)
// with coalesced loads, so the random row-gathers become local-L2 hits
// instead of L2 misses. Cross-XCD per-sample partials combine via atomicAdd
// into a zeroed f32 workspace; epilogue adds Wl/bias/sigmoid.

#define FF 20
#define V_FIELD 5000
#define TOTAL (FF * V_FIELD)   // 100000
#define DD 64
#define ROW_B 256              // DD * 4 bytes per embedding row
#define NP 190                 // F*(F-1)/2
#define NXCD 8
#define SPB 32                 // samples per block
#define MAXPP 24               // max pairs per XCD class (190 = 6*24 + 2*23)
#define SLICE_F4 80000         // float4s per 1.28 MB ordered-combo slice

__global__ __launch_bounds__(256, 4) void ffm_pairs(
    const int* __restrict__ x,
    const float* __restrict__ W,
    float* __restrict__ ws)
{
    __shared__ int g[SPB][FF];
    __shared__ int pii[MAXPP], pjj[MAXPP];
    __shared__ unsigned bA[MAXPP], bB[MAXPP], wA[MAXPP], wB[MAXPP];
    __shared__ unsigned offA[SPB][MAXPP], offB[SPB][MAXPP];

    const int t   = threadIdx.x;
    const int n   = blockIdx.x;
    const int xcd = n & 7;          // pair-class; matches HW round-robin XCD
    const int c   = n >> 3;         // sample chunk [0,256)
    const int s0g = c * SPB;
    const int npx = (NP - xcd + NXCD - 1) / NXCD;   // 24 for xcd<6 else 23

    // Stage sample vocab indices.
    for (int u = t; u < SPB * FF; u += 256) {
        const int s = u / FF, f = u - s * FF;
        g[s][f] = x[(s0g + s) * FF + f] + f * V_FIELD;
    }
    // Decode this class's pairs: p = xcd + 8*q.
    if (t < npx) {
        int p = xcd + t * NXCD;
        int pp = p, i = 0;
        while (pp >= FF - 1 - i) { pp -= FF - 1 - i; ++i; }
        const int j = i + 1 + pp;
        pii[t] = i; pjj[t] = j;
        const unsigned a  = (unsigned)(j * TOTAL) * ROW_B;  // table j (rows g_i)
        const unsigned b2 = (unsigned)(i * TOTAL) * ROW_B;  // table i (rows g_j)
        bA[t] = a;  bB[t] = b2;
        wA[t] = a  + (unsigned)(i * V_FIELD) * ROW_B;       // slice A start
        wB[t] = b2 + (unsigned)(j * V_FIELD) * ROW_B;       // slice B start
    }
    __syncthreads();

    // Per-(sample,pair) byte offsets (u32; table is 512 MB max).
    for (int u = t; u < SPB * npx; u += 256) {
        const int s = u / npx, q = u - s * npx;
        offA[s][q] = bA[q] + ((unsigned)g[s][pii[q]] << 8);
        offB[s][q] = bB[q] + ((unsigned)g[s][pjj[q]] << 8);
    }
    __syncthreads();

    const int lane = t & 63;
    const int wave = t >> 6;
    const int grp  = lane >> 4;                // 4 samples served per wave-load
    const unsigned chunk = (lane & 15) * 16;   // float4 slot within 256B row
    const int sA = wave * 8 + grp;             // this lane's sample slot, r=0
    const int sB = sA + 4;                     // r=1
    const char* Wb = (const char*)W;
    // Warm-lane id within the XCD class (256 blocks x 256 threads).
    const unsigned wl = ((unsigned)c << 8) | (unsigned)t;   // [0, 65536)

    float a00=0.f, a01=0.f, a02=0.f, a03=0.f;
    float a10=0.f, a11=0.f, a12=0.f, a13=0.f;
    float wk = 0.f;

    for (int q = 0; q < npx; ++q) {
        // Warm: coalesced streaming of this pair's two 1.28 MB slices into
        // the local L2, striped across the class's 256 blocks.
        {
            const float4* fA = (const float4*)(Wb + wA[q]);
            const float4* fB = (const float4*)(Wb + wB[q]);
            const float4 u0 = fA[wl];
            const float4 u1 = fB[wl];
            wk += (u0.x + u0.y) + (u0.z + u0.w)
                + (u1.x + u1.y) + (u1.z + u1.w);
            if (wl < (unsigned)(SLICE_F4 - 65536)) {   // tail 14464 f4s
                const float4 u2 = fA[wl + 65536u];
                const float4 u3 = fB[wl + 65536u];
                wk += (u2.x + u2.y) + (u2.z + u2.w)
                    + (u3.x + u3.y) + (u3.z + u3.w);
            }
        }
        // Gather + dot (should hit local L2).
        const float4 va0 = *(const float4*)(Wb + (offA[sA][q] + chunk));
        const float4 vb0 = *(const float4*)(Wb + (offB[sA][q] + chunk));
        const float4 va1 = *(const float4*)(Wb + (offA[sB][q] + chunk));
        const float4 vb1 = *(const float4*)(Wb + (offB[sB][q] + chunk));
        a00 = fmaf(va0.x, vb0.x, a00);
        a01 = fmaf(va0.y, vb0.y, a01);
        a02 = fmaf(va0.z, vb0.z, a02);
        a03 = fmaf(va0.w, vb0.w, a03);
        a10 = fmaf(va1.x, vb1.x, a10);
        a11 = fmaf(va1.y, vb1.y, a11);
        a12 = fmaf(va1.z, vb1.z, a12);
        a13 = fmaf(va1.w, vb1.w, a13);
    }

    // Keep warm loads live without affecting results (guide rule #17).
    asm volatile("" :: "v"(wk));

    float r0 = (a00 + a01) + (a02 + a03);
    float r1 = (a10 + a11) + (a12 + a13);
#pragma unroll
    for (int off = 8; off > 0; off >>= 1) {
        r0 += __shfl_xor(r0, off, 64);
        r1 += __shfl_xor(r1, off, 64);
    }
    if ((lane & 15) == 0) {
        atomicAdd(&ws[s0g + sA], r0);
        atomicAdd(&ws[s0g + sB], r1);
    }
}

__global__ __launch_bounds__(256) void ffm_final(
    const int* __restrict__ x,
    const float* __restrict__ Wl,
    const float* __restrict__ bias,
    const float* __restrict__ ws,
    float* __restrict__ out)
{
    const int b = blockIdx.x * 256 + threadIdx.x;
    float acc = ws[b] + bias[0];
#pragma unroll
    for (int f = 0; f < FF; ++f)
        acc += Wl[x[b * FF + f] + f * V_FIELD];
    out[b] = 1.f / (1.f + expf(-acc));
}

extern "C" void kernel_launch(void* const* d_in, const int* in_sizes, int n_in,
                              void* d_out, int out_size, void* d_ws, size_t ws_size,
                              hipStream_t stream) {
    const int*   x    = (const int*)d_in[0];
    const float* W    = (const float*)d_in[1];
    const float* Wl   = (const float*)d_in[2];
    const float* bias = (const float*)d_in[3];
    float* out = (float*)d_out;

    const int nB = out_size;            // 8192 samples
    float* wsf = (float*)d_ws;

    hipMemsetAsync(wsf, 0, nB * sizeof(float), stream);

    const int nchunk = nB / SPB;        // 256
    hipLaunchKernelGGL(ffm_pairs, dim3(nchunk * NXCD), dim3(256), 0, stream,
                       x, W, wsf);
    hipLaunchKernelGGL(ffm_final, dim3(nB / 256), dim3(256), 0, stream,
                       x, Wl, bias, wsf, out);
}